// Round 12
// baseline (120.478 us; speedup 1.0000x reference)
//
#include <hip/hip_runtime.h>
#include <hip/hip_bf16.h>

#define BATCH 8
#define CDIM  128
#define DK    16
#define NPIX  4096

typedef __attribute__((ext_vector_type(4)))  float    f32x4;
typedef __attribute__((ext_vector_type(8)))  short    s16x8;
typedef __attribute__((ext_vector_type(4)))  unsigned u32x4;

__device__ __forceinline__ short f2bf(float f) {
    union { float fv; unsigned u; } un; un.fv = f;
    unsigned r = un.u + 0x7FFFu + ((un.u >> 16) & 1u);   // RTNE
    return (short)(r >> 16);
}
__device__ __forceinline__ float bf2f(short s) {
    union { unsigned u; float f; } un; un.u = ((unsigned)(unsigned short)s) << 16;
    return un.f;
}
__device__ __forceinline__ float fexp2(float x) {
#if __has_builtin(__builtin_amdgcn_exp2f)
    return __builtin_amdgcn_exp2f(x);
#else
    return exp2f(x);
#endif
}
__device__ __forceinline__ unsigned pkbf(float lo, float hi) {
    __hip_bfloat162 h = __float22bfloat162_rn(make_float2(lo, hi));
    return *reinterpret_cast<unsigned*>(&h);
}

#define C2F 0.36067376022224085f   // log2(e)/4
#define WPFRAGS (10 * 4 * 64)      // mt x kt x lane

// ---------------------------------------------------------------------------
// Kernel 0: pack weights fragment-ready bf16 (unchanged).
// ---------------------------------------------------------------------------
__global__ __launch_bounds__(256) void wprep(
    const float* __restrict__ wq, const float* __restrict__ wk,
    const float* __restrict__ wv, short* __restrict__ Wp)
{
    const int mt   = blockIdx.x;          // 0..9
    const int t    = threadIdx.x;
    const int kt   = t >> 6;
    const int lane = t & 63;
    const int m    = mt * 16 + (lane & 15);
    const int c0   = kt * 32 + ((lane >> 4) << 3);

    const float* src; float scl = 1.f;
    if (m < 16)      { src = wq + m * CDIM; scl = C2F; }
    else if (m < 32) { src = wk + (m - 16) * CDIM; }
    else             { src = wv + (m - 32) * CDIM; }

    s16x8 frag;
    #pragma unroll
    for (int i = 0; i < 8; ++i) frag[i] = f2bf(src[c0 + i] * scl);
    *(s16x8*)(Wp + (((size_t)(mt * 4 + kt) * 64 + lane) << 3)) = frag;
}

// ---------------------------------------------------------------------------
// Kernel 1: QKV projection via MFMA, no LDS (unchanged from R9).
// V written FRAGMENT-PACKED: Vp[b][t=n>>6][ch=(n>>3)&7][c][j=n&7].
// ---------------------------------------------------------------------------
__global__ __launch_bounds__(256) void qkv_proj(
    const float* __restrict__ x, const short* __restrict__ Wp,
    const float* __restrict__ bq, const float* __restrict__ bk,
    const float* __restrict__ bv,
    short* __restrict__ Qt, short* __restrict__ Kt, short* __restrict__ Vp)
{
    const int tid   = threadIdx.x;
    const int bid   = blockIdx.x;
    const int b     = bid >> 6;
    const int nbase = (bid & 63) << 6;

    const int lane = tid & 63;
    const int lo   = lane & 15;
    const int hi   = lane >> 4;
    const int n    = ((tid >> 6) << 4) + lo;    // pixel within block (0..63)
    const int ng   = nbase + n;

    const float* xb = x + (((size_t)(b * CDIM)) << 12) + ng;

    s16x8 bfr[4];
    #pragma unroll
    for (int kt = 0; kt < 4; ++kt) {
        const float* xp = xb + (((size_t)(kt * 32 + hi * 8)) << 12);
        float v0 = xp[0];
        float v1 = xp[(size_t)1 << 12];
        float v2 = xp[(size_t)2 << 12];
        float v3 = xp[(size_t)3 << 12];
        float v4 = xp[(size_t)4 << 12];
        float v5 = xp[(size_t)5 << 12];
        float v6 = xp[(size_t)6 << 12];
        float v7 = xp[(size_t)7 << 12];
        union { u32x4 u; s16x8 v; } pk;
        pk.u[0] = pkbf(v0, v1); pk.u[1] = pkbf(v2, v3);
        pk.u[2] = pkbf(v4, v5); pk.u[3] = pkbf(v6, v7);
        bfr[kt] = pk.v;
    }

    f32x4 acc[10];
    #pragma unroll
    for (int mt = 0; mt < 10; ++mt) { acc[mt][0]=0.f; acc[mt][1]=0.f; acc[mt][2]=0.f; acc[mt][3]=0.f; }

    #pragma unroll
    for (int kt = 0; kt < 4; ++kt) {
        #pragma unroll
        for (int mt = 0; mt < 10; ++mt) {
            const s16x8 af = *(const s16x8*)(Wp + (((size_t)(mt * 4 + kt) * 64 + lane) << 3));
            acc[mt] = __builtin_amdgcn_mfma_f32_16x16x32_bf16(af, bfr[kt], acc[mt], 0, 0, 0);
        }
    }

    const int m4 = hi << 2;
    {   // q rows (scaled): Qt[b][n][16]
        uint2 pk;
        pk.x = pkbf(acc[0][0] + bq[m4 + 0] * C2F, acc[0][1] + bq[m4 + 1] * C2F);
        pk.y = pkbf(acc[0][2] + bq[m4 + 2] * C2F, acc[0][3] + bq[m4 + 3] * C2F);
        *(uint2*)(Qt + ((((size_t)(b << 12)) + ng) << 4) + m4) = pk;
    }
    {   // k rows: Kt[b][n][16]
        uint2 pk;
        pk.x = pkbf(acc[1][0] + bk[m4 + 0], acc[1][1] + bk[m4 + 1]);
        pk.y = pkbf(acc[1][2] + bk[m4 + 2], acc[1][3] + bk[m4 + 3]);
        *(uint2*)(Kt + ((((size_t)(b << 12)) + ng) << 4) + m4) = pk;
    }
    // v rows, fragment-packed: Vp[(((b*64+t)*8+ch)*128 + c)*8 + j]
    {
        short* vpb = Vp + ((((size_t)(b * 64 + (ng >> 6)) * 8 + ((ng >> 3) & 7)) * 128) << 3)
                        + (ng & 7);
        #pragma unroll
        for (int mt = 2; mt < 10; ++mt) {
            #pragma unroll
            for (int r = 0; r < 4; ++r) {
                const int c = (mt - 2) * 16 + m4 + r;
                vpb[c << 3] = f2bf(acc[mt][r] + bv[c]);
            }
        }
    }
}

// ---------------------------------------------------------------------------
// Kernel 2: flash attention partial — 16 queries/wave, 16x16x32 MFMA family.
// NO LDS, NO BARRIERS.  Halves per-wave accumulator state (O: 32 regs,
// S: 16 regs) vs the 32x32 version, so 2x waves fit per SIMD (R11 diagnosis:
// occupancy was VGPR+AGPR-total capped at ~2.6 waves/SIMD).
// QK: S^T = mfma(K,Q); K A-rows loaded with sigma permutation
// sigma_f(rho) = (rho>>2)*8 + (f&1)*4 + (rho&3) (+32 for f>=2) so S^T's
// D-register layout == PV's B-fragment order (P stays in registers).
// K's unused k-half (dk=16 < K=32) multiplies qB's zeros -> K loads are
// UNCONDITIONAL (no divergence).  Fixed-max softmax (Q pre-scaled log2e/4).
// Layouts (verified this session): A row=lane&15,k=(lane>>4)*8+i;
// B col=lane&15, same k; C/D col=lane&15, row=(lane>>4)*4+reg.
// ---------------------------------------------------------------------------
template<int KSPLIT, bool DIRECT>
__global__ __launch_bounds__(256, 4) void attn_part(
    const short* __restrict__ Qt, const short* __restrict__ Kt,
    const short* __restrict__ Vp, const float* __restrict__ x,
    float* __restrict__ out, short* __restrict__ Op, float* __restrict__ lsum)
{
    constexpr int NKEY = NPIX / KSPLIT;
    constexpr int NT   = NKEY / 64;

    const int tid = threadIdx.x;
    const int bid = blockIdx.x;
    const int b   = bid & 7;              // XCD affinity
    const int qb  = (bid >> 3) & 63;
    const int kc  = bid >> 9;
    const int wv  = tid >> 6;
    const int lane = tid & 63;
    const int lo  = lane & 15;
    const int hi  = lane >> 4;            // 0..3
    const int q0  = qb * 64 + wv * 16;

    // Q B-frag: col=lo (query), k=hi*8+i (channel); dk=16 -> hi>=2 lanes zero
    s16x8 qB;
    #pragma unroll
    for (int i = 0; i < 8; ++i) qB[i] = 0;
    if (hi < 2)
        qB = *(const s16x8*)(Qt + (((size_t)(b << 12) + q0 + lo) << 4) + hi * 8);

    // K A-row permutation base: sigma depends on lo only
    const int pk0 = ((lo >> 2) << 3) + (lo & 3);
    const int jbase0 = kc * NKEY;

    // K frag pointer (advance 64 keys = 1024 shorts per tile); +hi*8 channel sel
    const short* kb = Kt + (((size_t)(b << 12) + jbase0 + pk0) << 4) + hi * 8;
    // V base: shorts strides  j:1 c:8 ch:1024 t:8192 b:524288 ; c = ct*16+lo
    const short* vb = Vp + (size_t)b * 524288 + (size_t)(jbase0 >> 6) * 8192 + lo * 8;

    f32x4 O[8];
    #pragma unroll
    for (int ct = 0; ct < 8; ++ct) { O[ct][0]=0.f; O[ct][1]=0.f; O[ct][2]=0.f; O[ct][3]=0.f; }
    float l_acc = 0.f;
    const f32x4 z4 = {0.f, 0.f, 0.f, 0.f};

    for (int t = 0; t < NT; ++t) {
        // ---- QK^T: 4 frags of 16 keys (sigma-permuted rows), unconditional loads
        const s16x8 k0 = *(const s16x8*)(kb);
        const s16x8 k1 = *(const s16x8*)(kb + (4  << 4));
        const s16x8 k2 = *(const s16x8*)(kb + (32 << 4));
        const s16x8 k3 = *(const s16x8*)(kb + (36 << 4));
        f32x4 s0 = __builtin_amdgcn_mfma_f32_16x16x32_bf16(k0, qB, z4, 0, 0, 0);
        f32x4 s1 = __builtin_amdgcn_mfma_f32_16x16x32_bf16(k1, qB, z4, 0, 0, 0);
        f32x4 s2 = __builtin_amdgcn_mfma_f32_16x16x32_bf16(k2, qB, z4, 0, 0, 0);
        f32x4 s3 = __builtin_amdgcn_mfma_f32_16x16x32_bf16(k3, qB, z4, 0, 0, 0);

        // ---- softmax numerators (fixed max), pack to PV B-frags in-register
        union { u32x4 u; s16x8 v; } pc0, pc1;
        {
            float a0 = fexp2(s0[0]), a1 = fexp2(s0[1]), a2 = fexp2(s0[2]), a3 = fexp2(s0[3]);
            float c0 = fexp2(s1[0]), c1 = fexp2(s1[1]), c2 = fexp2(s1[2]), c3 = fexp2(s1[3]);
            l_acc += ((a0 + a1) + (a2 + a3)) + ((c0 + c1) + (c2 + c3));
            pc0.u[0] = pkbf(a0, a1); pc0.u[1] = pkbf(a2, a3);
            pc0.u[2] = pkbf(c0, c1); pc0.u[3] = pkbf(c2, c3);
        }
        {
            float a0 = fexp2(s2[0]), a1 = fexp2(s2[1]), a2 = fexp2(s2[2]), a3 = fexp2(s2[3]);
            float c0 = fexp2(s3[0]), c1 = fexp2(s3[1]), c2 = fexp2(s3[2]), c3 = fexp2(s3[3]);
            l_acc += ((a0 + a1) + (a2 + a3)) + ((c0 + c1) + (c2 + c3));
            pc1.u[0] = pkbf(a0, a1); pc1.u[1] = pkbf(a2, a3);
            pc1.u[2] = pkbf(c0, c1); pc1.u[3] = pkbf(c2, c3);
        }

        // ---- PV: O[ct][q] += V[c][k] * P[k][q], 2 K=32 chunks (ch=hi / hi+4)
        __builtin_amdgcn_s_setprio(1);
        #pragma unroll
        for (int ct = 0; ct < 8; ++ct) {
            const s16x8 v0 = *(const s16x8*)(vb + (size_t)(hi    ) * 1024 + ct * 128);
            const s16x8 v1 = *(const s16x8*)(vb + (size_t)(hi + 4) * 1024 + ct * 128);
            O[ct] = __builtin_amdgcn_mfma_f32_16x16x32_bf16(v0, pc0.v, O[ct], 0, 0, 0);
            O[ct] = __builtin_amdgcn_mfma_f32_16x16x32_bf16(v1, pc1.v, O[ct], 0, 0, 0);
        }
        __builtin_amdgcn_s_setprio(0);

        kb += 1024;      // next 64 keys
        vb += 8192;      // next V tile
    }

    // l: sum over this lane's 16 keys is in l_acc; reduce across hi groups
    float l_tot = l_acc;
    l_tot += __shfl_xor(l_tot, 16);
    l_tot += __shfl_xor(l_tot, 32);
    const int ncol = q0 + lo;

    if constexpr (DIRECT) {
        const float inv = 1.f / l_tot;
        #pragma unroll
        for (int ct = 0; ct < 8; ++ct) {
            #pragma unroll
            for (int r = 0; r < 4; ++r) {
                const int c = ct * 16 + hi * 4 + r;
                const size_t off = (((size_t)(b * CDIM + c)) << 12) + ncol;
                out[off] = O[ct][r] * inv + x[off];
            }
        }
    } else {
        const int prow = (kc * 8 + b) * CDIM;
        #pragma unroll
        for (int ct = 0; ct < 8; ++ct) {
            #pragma unroll
            for (int r = 0; r < 4; ++r) {
                const int c = ct * 16 + hi * 4 + r;
                Op[(((size_t)(prow + c)) << 12) + ncol] = f2bf(O[ct][r]);
            }
        }
        if (hi == 0) lsum[(((size_t)(kc * 8 + b)) << 12) + ncol] = l_tot;
    }
}

// ---------------------------------------------------------------------------
// Kernel 3: combine split-K partials: out = (sum_k Op_k) / (sum_k l_k) + x
// ---------------------------------------------------------------------------
template<int KSPLIT>
__global__ __launch_bounds__(256) void attn_combine(
    const short* __restrict__ Op, const float* __restrict__ lsum,
    const float* __restrict__ x, float* __restrict__ out)
{
    __shared__ float linv[256];
    const int tid = threadIdx.x;
    const int bid = blockIdx.x;
    const int b   = bid >> 7;
    const int nb  = (bid >> 3) & 15;
    const int cb  = bid & 7;
    const int nbase = nb << 8;

    {
        float s = 0.f;
        #pragma unroll
        for (int k = 0; k < KSPLIT; ++k)
            s += lsum[(((size_t)(k * 8 + b)) << 12) + nbase + tid];
        linv[tid] = 1.f / s;
    }
    __syncthreads();

    const int n8 = (tid & 31) << 3;
    #pragma unroll
    for (int pass = 0; pass < 2; ++pass) {
        const int c = (cb << 4) + (pass << 3) + (tid >> 5);
        const size_t gbase = (((size_t)(b * CDIM + c)) << 12) + nbase + n8;
        float acc[8];
        #pragma unroll
        for (int j = 0; j < 8; ++j) acc[j] = 0.f;
        #pragma unroll
        for (int k = 0; k < KSPLIT; ++k) {
            s16x8 v = *(const s16x8*)(Op + (((size_t)((k * 8 + b) * CDIM + c)) << 12) + nbase + n8);
            #pragma unroll
            for (int j = 0; j < 8; ++j) acc[j] += bf2f(v[j]);
        }
        float4 li0 = *(const float4*)&linv[n8];
        float4 li1 = *(const float4*)&linv[n8 + 4];
        float4 x0  = *(const float4*)(x + gbase);
        float4 x1  = *(const float4*)(x + gbase + 4);
        float4 o0, o1;
        o0.x = acc[0] * li0.x + x0.x;  o0.y = acc[1] * li0.y + x0.y;
        o0.z = acc[2] * li0.z + x0.z;  o0.w = acc[3] * li0.w + x0.w;
        o1.x = acc[4] * li1.x + x1.x;  o1.y = acc[5] * li1.y + x1.y;
        o1.z = acc[6] * li1.z + x1.z;  o1.w = acc[7] * li1.w + x1.w;
        *(float4*)(out + gbase)     = o0;
        *(float4*)(out + gbase + 4) = o1;
    }
}

// ---------------------------------------------------------------------------
extern "C" void kernel_launch(void* const* d_in, const int* in_sizes, int n_in,
                              void* d_out, int out_size, void* d_ws, size_t ws_size,
                              hipStream_t stream) {
    const float* x  = (const float*)d_in[0];
    const float* wq = (const float*)d_in[1];
    const float* bq = (const float*)d_in[2];
    const float* wk = (const float*)d_in[3];
    const float* bk = (const float*)d_in[4];
    const float* wv = (const float*)d_in[5];
    const float* bv = (const float*)d_in[6];
    float* out = (float*)d_out;

    short* Qt = (short*)d_ws;                          // [8][4096][16] bf16, 1 MB
    short* Kt = Qt + (size_t)BATCH * NPIX * DK;        // [8][4096][16] bf16, 1 MB
    short* Vp = Kt + (size_t)BATCH * NPIX * DK;        // fragment-packed V, 8 MB
    short* Wpk = Vp + (size_t)BATCH * CDIM * NPIX;     // packed weights, 40 KB
    char*  extra = (char*)(Wpk + (size_t)WPFRAGS * 8);
    const size_t used    = (size_t)(extra - (char*)d_ws);
    const size_t opBytes = (size_t)BATCH * CDIM * NPIX * sizeof(short); // 8 MB
    const size_t lBytes  = (size_t)BATCH * NPIX * sizeof(float);        // 128 KB

    wprep<<<dim3(10), dim3(256), 0, stream>>>(wq, wk, wv, Wpk);
    qkv_proj<<<dim3(512), dim3(256), 0, stream>>>(x, Wpk, bq, bk, bv, Qt, Kt, Vp);

    if (used + 4 * (opBytes + lBytes) <= ws_size) {
        short* Opw = (short*)extra;
        float* ls  = (float*)(extra + 4 * opBytes);
        attn_part<4, false><<<dim3(8 * 64 * 4), dim3(256), 0, stream>>>(Qt, Kt, Vp, x, out, Opw, ls);
        attn_combine<4><<<dim3(1024), dim3(256), 0, stream>>>(Opw, ls, x, out);
    } else if (used + 2 * (opBytes + lBytes) <= ws_size) {
        short* Opw = (short*)extra;
        float* ls  = (float*)(extra + 2 * opBytes);
        attn_part<2, false><<<dim3(8 * 64 * 2), dim3(256), 0, stream>>>(Qt, Kt, Vp, x, out, Opw, ls);
        attn_combine<2><<<dim3(1024), dim3(256), 0, stream>>>(Opw, ls, x, out);
    } else {
        attn_part<1, true><<<dim3(8 * 64), dim3(256), 0, stream>>>(Qt, Kt, Vp, x, out, nullptr, nullptr);
    }
}

// Round 13
// 119.810 us; speedup vs baseline: 1.0056x; 1.0056x over previous
//
#include <hip/hip_runtime.h>
#include <hip/hip_bf16.h>

#define BATCH 8
#define CDIM  128
#define DK    16
#define NPIX  4096

typedef __attribute__((ext_vector_type(4)))  float    f32x4;
typedef __attribute__((ext_vector_type(8)))  short    s16x8;
typedef __attribute__((ext_vector_type(4)))  unsigned u32x4;

__device__ __forceinline__ short f2bf(float f) {
    union { float fv; unsigned u; } un; un.fv = f;
    unsigned r = un.u + 0x7FFFu + ((un.u >> 16) & 1u);   // RTNE
    return (short)(r >> 16);
}
__device__ __forceinline__ float bf2f(short s) {
    union { unsigned u; float f; } un; un.u = ((unsigned)(unsigned short)s) << 16;
    return un.f;
}
__device__ __forceinline__ float fexp2(float x) {
#if __has_builtin(__builtin_amdgcn_exp2f)
    return __builtin_amdgcn_exp2f(x);
#else
    return exp2f(x);
#endif
}
__device__ __forceinline__ unsigned pkbf(float lo, float hi) {
    __hip_bfloat162 h = __float22bfloat162_rn(make_float2(lo, hi));
    return *reinterpret_cast<unsigned*>(&h);
}

#define C2F 0.36067376022224085f   // log2(e)/4
#define WPFRAGS (10 * 4 * 64)      // mt x kt x lane

// ---------------------------------------------------------------------------
// Kernel 0: pack weights fragment-ready bf16 (unchanged).
// ---------------------------------------------------------------------------
__global__ __launch_bounds__(256) void wprep(
    const float* __restrict__ wq, const float* __restrict__ wk,
    const float* __restrict__ wv, short* __restrict__ Wp)
{
    const int mt   = blockIdx.x;          // 0..9
    const int t    = threadIdx.x;
    const int kt   = t >> 6;
    const int lane = t & 63;
    const int m    = mt * 16 + (lane & 15);
    const int c0   = kt * 32 + ((lane >> 4) << 3);

    const float* src; float scl = 1.f;
    if (m < 16)      { src = wq + m * CDIM; scl = C2F; }
    else if (m < 32) { src = wk + (m - 16) * CDIM; }
    else             { src = wv + (m - 32) * CDIM; }

    s16x8 frag;
    #pragma unroll
    for (int i = 0; i < 8; ++i) frag[i] = f2bf(src[c0 + i] * scl);
    *(s16x8*)(Wp + (((size_t)(mt * 4 + kt) * 64 + lane) << 3)) = frag;
}

// ---------------------------------------------------------------------------
// Kernel 1: QKV projection via MFMA, no LDS (unchanged from R9).
// V written FRAGMENT-PACKED: Vp[b][t=n>>6][ch=(n>>3)&7][c][j=n&7].
// ---------------------------------------------------------------------------
__global__ __launch_bounds__(256) void qkv_proj(
    const float* __restrict__ x, const short* __restrict__ Wp,
    const float* __restrict__ bq, const float* __restrict__ bk,
    const float* __restrict__ bv,
    short* __restrict__ Qt, short* __restrict__ Kt, short* __restrict__ Vp)
{
    const int tid   = threadIdx.x;
    const int bid   = blockIdx.x;
    const int b     = bid >> 6;
    const int nbase = (bid & 63) << 6;

    const int lane = tid & 63;
    const int lo   = lane & 15;
    const int hi   = lane >> 4;
    const int n    = ((tid >> 6) << 4) + lo;    // pixel within block (0..63)
    const int ng   = nbase + n;

    const float* xb = x + (((size_t)(b * CDIM)) << 12) + ng;

    s16x8 bfr[4];
    #pragma unroll
    for (int kt = 0; kt < 4; ++kt) {
        const float* xp = xb + (((size_t)(kt * 32 + hi * 8)) << 12);
        float v0 = xp[0];
        float v1 = xp[(size_t)1 << 12];
        float v2 = xp[(size_t)2 << 12];
        float v3 = xp[(size_t)3 << 12];
        float v4 = xp[(size_t)4 << 12];
        float v5 = xp[(size_t)5 << 12];
        float v6 = xp[(size_t)6 << 12];
        float v7 = xp[(size_t)7 << 12];
        union { u32x4 u; s16x8 v; } pk;
        pk.u[0] = pkbf(v0, v1); pk.u[1] = pkbf(v2, v3);
        pk.u[2] = pkbf(v4, v5); pk.u[3] = pkbf(v6, v7);
        bfr[kt] = pk.v;
    }

    f32x4 acc[10];
    #pragma unroll
    for (int mt = 0; mt < 10; ++mt) { acc[mt][0]=0.f; acc[mt][1]=0.f; acc[mt][2]=0.f; acc[mt][3]=0.f; }

    #pragma unroll
    for (int kt = 0; kt < 4; ++kt) {
        #pragma unroll
        for (int mt = 0; mt < 10; ++mt) {
            const s16x8 af = *(const s16x8*)(Wp + (((size_t)(mt * 4 + kt) * 64 + lane) << 3));
            acc[mt] = __builtin_amdgcn_mfma_f32_16x16x32_bf16(af, bfr[kt], acc[mt], 0, 0, 0);
        }
    }

    const int m4 = hi << 2;
    {   // q rows (scaled): Qt[b][n][16]
        uint2 pk;
        pk.x = pkbf(acc[0][0] + bq[m4 + 0] * C2F, acc[0][1] + bq[m4 + 1] * C2F);
        pk.y = pkbf(acc[0][2] + bq[m4 + 2] * C2F, acc[0][3] + bq[m4 + 3] * C2F);
        *(uint2*)(Qt + ((((size_t)(b << 12)) + ng) << 4) + m4) = pk;
    }
    {   // k rows: Kt[b][n][16]
        uint2 pk;
        pk.x = pkbf(acc[1][0] + bk[m4 + 0], acc[1][1] + bk[m4 + 1]);
        pk.y = pkbf(acc[1][2] + bk[m4 + 2], acc[1][3] + bk[m4 + 3]);
        *(uint2*)(Kt + ((((size_t)(b << 12)) + ng) << 4) + m4) = pk;
    }
    // v rows, fragment-packed: Vp[(((b*64+t)*8+ch)*128 + c)*8 + j]
    {
        short* vpb = Vp + ((((size_t)(b * 64 + (ng >> 6)) * 8 + ((ng >> 3) & 7)) * 128) << 3)
                        + (ng & 7);
        #pragma unroll
        for (int mt = 2; mt < 10; ++mt) {
            #pragma unroll
            for (int r = 0; r < 4; ++r) {
                const int c = (mt - 2) * 16 + m4 + r;
                vpb[c << 3] = f2bf(acc[mt][r] + bv[c]);
            }
        }
    }
}

// ---------------------------------------------------------------------------
// Kernel 2: flash attention partial — 16 queries/wave, 16x16x32 MFMA family.
// NO LDS, NO BARRIERS.  Halves per-wave accumulator state (O: 32 regs,
// S: 16 regs) vs the 32x32 version, so 2x waves fit per SIMD (R11 diagnosis:
// occupancy was VGPR+AGPR-total capped at ~2.6 waves/SIMD).
// QK: S^T = mfma(K,Q); K A-rows loaded with sigma permutation
// sigma_f(rho) = (rho>>2)*8 + (f&1)*4 + (rho&3) (+32 for f>=2) so S^T's
// D-register layout == PV's B-fragment order (P stays in registers).
// K's unused k-half (dk=16 < K=32) multiplies qB's zeros -> K loads are
// UNCONDITIONAL (no divergence).  Fixed-max softmax (Q pre-scaled log2e/4).
// Layouts (verified this session): A row=lane&15,k=(lane>>4)*8+i;
// B col=lane&15, same k; C/D col=lane&15, row=(lane>>4)*4+reg.
// ---------------------------------------------------------------------------
template<int KSPLIT, bool DIRECT>
__global__ __launch_bounds__(256, 4) void attn_part(
    const short* __restrict__ Qt, const short* __restrict__ Kt,
    const short* __restrict__ Vp, const float* __restrict__ x,
    float* __restrict__ out, short* __restrict__ Op, float* __restrict__ lsum)
{
    constexpr int NKEY = NPIX / KSPLIT;
    constexpr int NT   = NKEY / 64;

    const int tid = threadIdx.x;
    const int bid = blockIdx.x;
    const int b   = bid & 7;              // XCD affinity
    const int qb  = (bid >> 3) & 63;
    const int kc  = bid >> 9;
    const int wv  = tid >> 6;
    const int lane = tid & 63;
    const int lo  = lane & 15;
    const int hi  = lane >> 4;            // 0..3
    const int q0  = qb * 64 + wv * 16;

    // Q B-frag: col=lo (query), k=hi*8+i (channel); dk=16 -> hi>=2 lanes zero
    s16x8 qB;
    #pragma unroll
    for (int i = 0; i < 8; ++i) qB[i] = 0;
    if (hi < 2)
        qB = *(const s16x8*)(Qt + (((size_t)(b << 12) + q0 + lo) << 4) + hi * 8);

    // K A-row permutation base: sigma depends on lo only
    const int pk0 = ((lo >> 2) << 3) + (lo & 3);
    const int jbase0 = kc * NKEY;

    // K frag pointer (advance 64 keys = 1024 shorts per tile); +hi*8 channel sel
    const short* kb = Kt + (((size_t)(b << 12) + jbase0 + pk0) << 4) + hi * 8;
    // V base: shorts strides  j:1 c:8 ch:1024 t:8192 b:524288 ; c = ct*16+lo
    const short* vb = Vp + (size_t)b * 524288 + (size_t)(jbase0 >> 6) * 8192 + lo * 8;

    f32x4 O[8];
    #pragma unroll
    for (int ct = 0; ct < 8; ++ct) { O[ct][0]=0.f; O[ct][1]=0.f; O[ct][2]=0.f; O[ct][3]=0.f; }
    float l_acc = 0.f;
    const f32x4 z4 = {0.f, 0.f, 0.f, 0.f};

    for (int t = 0; t < NT; ++t) {
        // ---- QK^T: 4 frags of 16 keys (sigma-permuted rows), unconditional loads
        const s16x8 k0 = *(const s16x8*)(kb);
        const s16x8 k1 = *(const s16x8*)(kb + (4  << 4));
        const s16x8 k2 = *(const s16x8*)(kb + (32 << 4));
        const s16x8 k3 = *(const s16x8*)(kb + (36 << 4));
        f32x4 s0 = __builtin_amdgcn_mfma_f32_16x16x32_bf16(k0, qB, z4, 0, 0, 0);
        f32x4 s1 = __builtin_amdgcn_mfma_f32_16x16x32_bf16(k1, qB, z4, 0, 0, 0);
        f32x4 s2 = __builtin_amdgcn_mfma_f32_16x16x32_bf16(k2, qB, z4, 0, 0, 0);
        f32x4 s3 = __builtin_amdgcn_mfma_f32_16x16x32_bf16(k3, qB, z4, 0, 0, 0);

        // ---- softmax numerators (fixed max), pack to PV B-frags in-register
        union { u32x4 u; s16x8 v; } pc0, pc1;
        {
            float a0 = fexp2(s0[0]), a1 = fexp2(s0[1]), a2 = fexp2(s0[2]), a3 = fexp2(s0[3]);
            float c0 = fexp2(s1[0]), c1 = fexp2(s1[1]), c2 = fexp2(s1[2]), c3 = fexp2(s1[3]);
            l_acc += ((a0 + a1) + (a2 + a3)) + ((c0 + c1) + (c2 + c3));
            pc0.u[0] = pkbf(a0, a1); pc0.u[1] = pkbf(a2, a3);
            pc0.u[2] = pkbf(c0, c1); pc0.u[3] = pkbf(c2, c3);
        }
        {
            float a0 = fexp2(s2[0]), a1 = fexp2(s2[1]), a2 = fexp2(s2[2]), a3 = fexp2(s2[3]);
            float c0 = fexp2(s3[0]), c1 = fexp2(s3[1]), c2 = fexp2(s3[2]), c3 = fexp2(s3[3]);
            l_acc += ((a0 + a1) + (a2 + a3)) + ((c0 + c1) + (c2 + c3));
            pc1.u[0] = pkbf(a0, a1); pc1.u[1] = pkbf(a2, a3);
            pc1.u[2] = pkbf(c0, c1); pc1.u[3] = pkbf(c2, c3);
        }

        // ---- PV: O[ct][q] += V[c][k] * P[k][q], 2 K=32 chunks (ch=hi / hi+4)
        __builtin_amdgcn_s_setprio(1);
        #pragma unroll
        for (int ct = 0; ct < 8; ++ct) {
            const s16x8 v0 = *(const s16x8*)(vb + (size_t)(hi    ) * 1024 + ct * 128);
            const s16x8 v1 = *(const s16x8*)(vb + (size_t)(hi + 4) * 1024 + ct * 128);
            O[ct] = __builtin_amdgcn_mfma_f32_16x16x32_bf16(v0, pc0.v, O[ct], 0, 0, 0);
            O[ct] = __builtin_amdgcn_mfma_f32_16x16x32_bf16(v1, pc1.v, O[ct], 0, 0, 0);
        }
        __builtin_amdgcn_s_setprio(0);

        kb += 1024;      // next 64 keys
        vb += 8192;      // next V tile
    }

    // l: sum over this lane's 16 keys is in l_acc; reduce across hi groups
    float l_tot = l_acc;
    l_tot += __shfl_xor(l_tot, 16);
    l_tot += __shfl_xor(l_tot, 32);
    const int ncol = q0 + lo;

    if constexpr (DIRECT) {
        const float inv = 1.f / l_tot;
        #pragma unroll
        for (int ct = 0; ct < 8; ++ct) {
            #pragma unroll
            for (int r = 0; r < 4; ++r) {
                const int c = ct * 16 + hi * 4 + r;
                const size_t off = (((size_t)(b * CDIM + c)) << 12) + ncol;
                out[off] = O[ct][r] * inv + x[off];
            }
        }
    } else {
        const int prow = (kc * 8 + b) * CDIM;
        #pragma unroll
        for (int ct = 0; ct < 8; ++ct) {
            #pragma unroll
            for (int r = 0; r < 4; ++r) {
                const int c = ct * 16 + hi * 4 + r;
                Op[(((size_t)(prow + c)) << 12) + ncol] = f2bf(O[ct][r]);
            }
        }
        if (hi == 0) lsum[(((size_t)(kc * 8 + b)) << 12) + ncol] = l_tot;
    }
}

// ---------------------------------------------------------------------------
// Kernel 3: combine split-K partials: out = (sum_k Op_k) / (sum_k l_k) + x
// ---------------------------------------------------------------------------
template<int KSPLIT>
__global__ __launch_bounds__(256) void attn_combine(
    const short* __restrict__ Op, const float* __restrict__ lsum,
    const float* __restrict__ x, float* __restrict__ out)
{
    __shared__ float linv[256];
    const int tid = threadIdx.x;
    const int bid = blockIdx.x;
    const int b   = bid >> 7;
    const int nb  = (bid >> 3) & 15;
    const int cb  = bid & 7;
    const int nbase = nb << 8;

    {
        float s = 0.f;
        #pragma unroll
        for (int k = 0; k < KSPLIT; ++k)
            s += lsum[(((size_t)(k * 8 + b)) << 12) + nbase + tid];
        linv[tid] = 1.f / s;
    }
    __syncthreads();

    const int n8 = (tid & 31) << 3;
    #pragma unroll
    for (int pass = 0; pass < 2; ++pass) {
        const int c = (cb << 4) + (pass << 3) + (tid >> 5);
        const size_t gbase = (((size_t)(b * CDIM + c)) << 12) + nbase + n8;
        float acc[8];
        #pragma unroll
        for (int j = 0; j < 8; ++j) acc[j] = 0.f;
        #pragma unroll
        for (int k = 0; k < KSPLIT; ++k) {
            s16x8 v = *(const s16x8*)(Op + (((size_t)((k * 8 + b) * CDIM + c)) << 12) + nbase + n8);
            #pragma unroll
            for (int j = 0; j < 8; ++j) acc[j] += bf2f(v[j]);
        }
        float4 li0 = *(const float4*)&linv[n8];
        float4 li1 = *(const float4*)&linv[n8 + 4];
        float4 x0  = *(const float4*)(x + gbase);
        float4 x1  = *(const float4*)(x + gbase + 4);
        float4 o0, o1;
        o0.x = acc[0] * li0.x + x0.x;  o0.y = acc[1] * li0.y + x0.y;
        o0.z = acc[2] * li0.z + x0.z;  o0.w = acc[3] * li0.w + x0.w;
        o1.x = acc[4] * li1.x + x1.x;  o1.y = acc[5] * li1.y + x1.y;
        o1.z = acc[6] * li1.z + x1.z;  o1.w = acc[7] * li1.w + x1.w;
        *(float4*)(out + gbase)     = o0;
        *(float4*)(out + gbase + 4) = o1;
    }
}

// ---------------------------------------------------------------------------
extern "C" void kernel_launch(void* const* d_in, const int* in_sizes, int n_in,
                              void* d_out, int out_size, void* d_ws, size_t ws_size,
                              hipStream_t stream) {
    const float* x  = (const float*)d_in[0];
    const float* wq = (const float*)d_in[1];
    const float* bq = (const float*)d_in[2];
    const float* wk = (const float*)d_in[3];
    const float* bk = (const float*)d_in[4];
    const float* wv = (const float*)d_in[5];
    const float* bv = (const float*)d_in[6];
    float* out = (float*)d_out;

    short* Qt = (short*)d_ws;                          // [8][4096][16] bf16, 1 MB
    short* Kt = Qt + (size_t)BATCH * NPIX * DK;        // [8][4096][16] bf16, 1 MB
    short* Vp = Kt + (size_t)BATCH * NPIX * DK;        // fragment-packed V, 8 MB
    short* Wpk = Vp + (size_t)BATCH * CDIM * NPIX;     // packed weights, 40 KB
    char*  extra = (char*)(Wpk + (size_t)WPFRAGS * 8);
    const size_t used    = (size_t)(extra - (char*)d_ws);
    const size_t opBytes = (size_t)BATCH * CDIM * NPIX * sizeof(short); // 8 MB
    const size_t lBytes  = (size_t)BATCH * NPIX * sizeof(float);        // 128 KB

    wprep<<<dim3(10), dim3(256), 0, stream>>>(wq, wk, wv, Wpk);
    qkv_proj<<<dim3(512), dim3(256), 0, stream>>>(x, Wpk, bq, bk, bv, Qt, Kt, Vp);

    if (used + 4 * (opBytes + lBytes) <= ws_size) {
        short* Opw = (short*)extra;
        float* ls  = (float*)(extra + 4 * opBytes);
        attn_part<4, false><<<dim3(8 * 64 * 4), dim3(256), 0, stream>>>(Qt, Kt, Vp, x, out, Opw, ls);
        attn_combine<4><<<dim3(1024), dim3(256), 0, stream>>>(Opw, ls, x, out);
    } else if (used + 2 * (opBytes + lBytes) <= ws_size) {
        short* Opw = (short*)extra;
        float* ls  = (float*)(extra + 2 * opBytes);
        attn_part<2, false><<<dim3(8 * 64 * 2), dim3(256), 0, stream>>>(Qt, Kt, Vp, x, out, Opw, ls);
        attn_combine<2><<<dim3(1024), dim3(256), 0, stream>>>(Opw, ls, x, out);
    } else {
        attn_part<1, true><<<dim3(8 * 64), dim3(256), 0, stream>>>(Qt, Kt, Vp, x, out, nullptr, nullptr);
    }
}

// Round 14
// 79.359 us; speedup vs baseline: 1.5181x; 1.5097x over previous
//
#include <hip/hip_runtime.h>
#include <hip/hip_bf16.h>

#define BATCH 8
#define CDIM  128
#define DK    16
#define NPIX  4096
#define VSTR  72   // V LDS row stride in shorts: 144B -> conflict-free b128 r/w (R8-verified)

typedef __attribute__((ext_vector_type(4)))  float    f32x4;
typedef __attribute__((ext_vector_type(16))) float    f32x16;
typedef __attribute__((ext_vector_type(8)))  short    s16x8;
typedef __attribute__((ext_vector_type(4)))  unsigned u32x4;

__device__ __forceinline__ short f2bf(float f) {
    union { float fv; unsigned u; } un; un.fv = f;
    unsigned r = un.u + 0x7FFFu + ((un.u >> 16) & 1u);   // RTNE
    return (short)(r >> 16);
}
__device__ __forceinline__ float bf2f(short s) {
    union { unsigned u; float f; } un; un.u = ((unsigned)(unsigned short)s) << 16;
    return un.f;
}
__device__ __forceinline__ float fexp2(float x) {
#if __has_builtin(__builtin_amdgcn_exp2f)
    return __builtin_amdgcn_exp2f(x);
#else
    return exp2f(x);
#endif
}
__device__ __forceinline__ unsigned pkbf(float lo, float hi) {
    __hip_bfloat162 h = __float22bfloat162_rn(make_float2(lo, hi));
    return *reinterpret_cast<unsigned*>(&h);
}
__device__ __forceinline__ f32x16 zero16() {
    f32x16 z;
    #pragma unroll
    for (int i = 0; i < 16; ++i) z[i] = 0.f;
    return z;
}

#define C2F 0.36067376022224085f   // log2(e)/4
#define WPFRAGS (10 * 4 * 64)      // mt x kt x lane

// ---------------------------------------------------------------------------
// Kernel 0: pack weights fragment-ready bf16 (unchanged).
// ---------------------------------------------------------------------------
__global__ __launch_bounds__(256) void wprep(
    const float* __restrict__ wq, const float* __restrict__ wk,
    const float* __restrict__ wv, short* __restrict__ Wp)
{
    const int mt   = blockIdx.x;          // 0..9
    const int t    = threadIdx.x;
    const int kt   = t >> 6;
    const int lane = t & 63;
    const int m    = mt * 16 + (lane & 15);
    const int c0   = kt * 32 + ((lane >> 4) << 3);

    const float* src; float scl = 1.f;
    if (m < 16)      { src = wq + m * CDIM; scl = C2F; }
    else if (m < 32) { src = wk + (m - 16) * CDIM; }
    else             { src = wv + (m - 32) * CDIM; }

    s16x8 frag;
    #pragma unroll
    for (int i = 0; i < 8; ++i) frag[i] = f2bf(src[c0 + i] * scl);
    *(s16x8*)(Wp + (((size_t)(mt * 4 + kt) * 64 + lane) << 3)) = frag;
}

// ---------------------------------------------------------------------------
// Kernel 1: QKV projection via MFMA, no LDS (R6 version: V plain [b][c][n]).
// ---------------------------------------------------------------------------
__global__ __launch_bounds__(256) void qkv_proj(
    const float* __restrict__ x, const short* __restrict__ Wp,
    const float* __restrict__ bq, const float* __restrict__ bk,
    const float* __restrict__ bv,
    short* __restrict__ Qt, short* __restrict__ Kt, short* __restrict__ Vb)
{
    const int tid   = threadIdx.x;
    const int bid   = blockIdx.x;
    const int b     = bid >> 6;
    const int nbase = (bid & 63) << 6;

    const int lane = tid & 63;
    const int lo   = lane & 15;
    const int hi   = lane >> 4;
    const int n    = ((tid >> 6) << 4) + lo;    // pixel within block (0..63)
    const int ng   = nbase + n;

    const float* xb = x + (((size_t)(b * CDIM)) << 12) + ng;

    s16x8 bfr[4];
    #pragma unroll
    for (int kt = 0; kt < 4; ++kt) {
        const float* xp = xb + (((size_t)(kt * 32 + hi * 8)) << 12);
        float v0 = xp[0];
        float v1 = xp[(size_t)1 << 12];
        float v2 = xp[(size_t)2 << 12];
        float v3 = xp[(size_t)3 << 12];
        float v4 = xp[(size_t)4 << 12];
        float v5 = xp[(size_t)5 << 12];
        float v6 = xp[(size_t)6 << 12];
        float v7 = xp[(size_t)7 << 12];
        union { u32x4 u; s16x8 v; } pk;
        pk.u[0] = pkbf(v0, v1); pk.u[1] = pkbf(v2, v3);
        pk.u[2] = pkbf(v4, v5); pk.u[3] = pkbf(v6, v7);
        bfr[kt] = pk.v;
    }

    f32x4 acc[10];
    #pragma unroll
    for (int mt = 0; mt < 10; ++mt) { acc[mt][0]=0.f; acc[mt][1]=0.f; acc[mt][2]=0.f; acc[mt][3]=0.f; }

    #pragma unroll
    for (int kt = 0; kt < 4; ++kt) {
        #pragma unroll
        for (int mt = 0; mt < 10; ++mt) {
            const s16x8 af = *(const s16x8*)(Wp + (((size_t)(mt * 4 + kt) * 64 + lane) << 3));
            acc[mt] = __builtin_amdgcn_mfma_f32_16x16x32_bf16(af, bfr[kt], acc[mt], 0, 0, 0);
        }
    }

    const int m4 = hi << 2;
    {   // q rows (scaled): Qt[b][n][16]
        uint2 pk;
        pk.x = pkbf(acc[0][0] + bq[m4 + 0] * C2F, acc[0][1] + bq[m4 + 1] * C2F);
        pk.y = pkbf(acc[0][2] + bq[m4 + 2] * C2F, acc[0][3] + bq[m4 + 3] * C2F);
        *(uint2*)(Qt + ((((size_t)(b << 12)) + ng) << 4) + m4) = pk;
    }
    {   // k rows: Kt[b][n][16]
        uint2 pk;
        pk.x = pkbf(acc[1][0] + bk[m4 + 0], acc[1][1] + bk[m4 + 1]);
        pk.y = pkbf(acc[1][2] + bk[m4 + 2], acc[1][3] + bk[m4 + 3]);
        *(uint2*)(Kt + ((((size_t)(b << 12)) + ng) << 4) + m4) = pk;
    }
    #pragma unroll
    for (int mt = 2; mt < 10; ++mt) {     // v rows: Vb[b][c][n]
        #pragma unroll
        for (int r = 0; r < 4; ++r) {
            const int c = (mt - 2) * 16 + m4 + r;
            Vb[(((size_t)(b * CDIM + c)) << 12) + ng] = f2bf(acc[mt][r] + bv[c]);
        }
    }
}

// ---------------------------------------------------------------------------
// Kernel 2: flash attention partial — R6 structure (session-best 55.5us)
// with ONLY the isolated conflict fix: VSTR=72 V-LDS layout (R8-verified:
// SQ_LDS_BANK_CONFLICT 4.19M -> 0) and setprio removed (m190: hurts
// barrier-synced lockstep waves).  No ones-MFMA (R8's confound, +21us).
// Double-buffered V (one barrier/tile), K prefetch, LOADVF one-HALF-ahead,
// (256,3): 170-reg budget, no spill.
// ---------------------------------------------------------------------------
template<int KSPLIT, bool DIRECT>
__global__ __launch_bounds__(256, 3) void attn_part(
    const short* __restrict__ Qt, const short* __restrict__ Kt,
    const short* __restrict__ Vb, const float* __restrict__ x,
    float* __restrict__ out, short* __restrict__ Op, float* __restrict__ lsum)
{
    constexpr int NKEY = NPIX / KSPLIT;
    constexpr int NT   = NKEY / 64;
    __shared__ __align__(16) short vs[2][CDIM * VSTR];   // 2 x 18 KB

    const int tid = threadIdx.x;
    const int bid = blockIdx.x;
    const int qb  = bid & 31;
    const int kc  = (bid >> 5) % KSPLIT;
    const int b   = bid / (32 * KSPLIT);
    const int q0  = qb * 128 + (tid >> 6) * 32;
    const int l31 = tid & 31;
    const int hi2 = (tid >> 5) & 1;
    const int kq  = hi2 << 3;
    // K-row lane permutation: swap bit2<->bit3 (pi(s+4)=pi(s)+8)
    const int pi  = (l31 & ~12) | ((l31 & 4) << 1) | ((l31 & 8) >> 1);

    const s16x8 qB = *(const s16x8*)(Qt + (((size_t)(b << 12) + q0 + l31) << 4) + kq);

    // V staging: thread -> (channel cb8 + 32*k, 16B chunk j8); VSTR rows are
    // conflict-free for both ds_write_b128 and ds_read_b128 (R8 measured 0)
    const int j8  = tid & 7;
    const int cb8 = tid >> 3;
    const short* vsrc = Vb + (((size_t)(b * CDIM + cb8)) << 12) + (j8 << 3);
    const int vdoff = cb8 * VSTR + (j8 << 3);
    const size_t cstr = (size_t)32 << 12;

    const int jbase0 = kc * NKEY;
    const short* ktb = Kt + ((size_t)(b << 12) << 4);

    f32x16 O0 = zero16(), O1 = zero16(), O2 = zero16(), O3 = zero16();
    float l_acc = 0.f;

    s16x8 r0, r1, r2, r3;
    #define VLOAD(jb) do {                                   \
        r0 = *(const s16x8*)(vsrc + (jb));                   \
        r1 = *(const s16x8*)(vsrc + (jb) + cstr);            \
        r2 = *(const s16x8*)(vsrc + (jb) + 2 * cstr);        \
        r3 = *(const s16x8*)(vsrc + (jb) + 3 * cstr);        \
    } while (0)
    #define VSTORE(bufi) do {                                \
        short* vd_ = &vs[bufi][vdoff];                       \
        *(s16x8*)(vd_)             = r0;                     \
        *(s16x8*)(vd_ + 32 * VSTR) = r1;                     \
        *(s16x8*)(vd_ + 64 * VSTR) = r2;                     \
        *(s16x8*)(vd_ + 96 * VSTR) = r3;                     \
    } while (0)
    #define KLOAD(jb) (*(const s16x8*)(ktb + (((size_t)((jb) + pi)) << 4) + kq))
    #define LDSV(vb_, ct, ch) (*(const s16x8*)((vb_) + ((ct) * 32 + l31) * VSTR + ((ch) << 3)))

    // h = jf*2+ktl; ch = (h<<1)|hi2; frags independent of S -> prefetchable
    #define LOADVF(dst, h, vb_) do {                         \
        const int ch_ = ((h) << 1) | hi2;                    \
        dst[0] = LDSV(vb_, 0, ch_);                          \
        dst[1] = LDSV(vb_, 1, ch_);                          \
        dst[2] = LDSV(vb_, 2, ch_);                          \
        dst[3] = LDSV(vb_, 3, ch_);                          \
    } while (0)

    #define HALFP(sv, ktl, vf) do {                                             \
        float p0 = fexp2(sv[8*(ktl)+0]), p1 = fexp2(sv[8*(ktl)+1]);            \
        float p2 = fexp2(sv[8*(ktl)+2]), p3 = fexp2(sv[8*(ktl)+3]);            \
        float p4 = fexp2(sv[8*(ktl)+4]), p5 = fexp2(sv[8*(ktl)+5]);            \
        float p6 = fexp2(sv[8*(ktl)+6]), p7 = fexp2(sv[8*(ktl)+7]);            \
        l_acc += ((p0+p1)+(p2+p3)) + ((p4+p5)+(p6+p7));                        \
        union { u32x4 u; s16x8 v; } pc_;                                       \
        pc_.u[0] = pkbf(p0,p1); pc_.u[1] = pkbf(p2,p3);                        \
        pc_.u[2] = pkbf(p4,p5); pc_.u[3] = pkbf(p6,p7);                        \
        O0 = __builtin_amdgcn_mfma_f32_32x32x16_bf16(vf[0], pc_.v, O0, 0,0,0); \
        O1 = __builtin_amdgcn_mfma_f32_32x32x16_bf16(vf[1], pc_.v, O1, 0,0,0); \
        O2 = __builtin_amdgcn_mfma_f32_32x32x16_bf16(vf[2], pc_.v, O2, 0,0,0); \
        O3 = __builtin_amdgcn_mfma_f32_32x32x16_bf16(vf[3], pc_.v, O3, 0,0,0); \
    } while (0)

    // prologue: stage tile 0, preload K(0)
    VLOAD(jbase0);
    s16x8 kA0c = KLOAD(jbase0);
    s16x8 kA1c = KLOAD(jbase0 + 32);
    VSTORE(0);
    __syncthreads();

    for (int t = 0; t < NT; ++t) {
        const int jb  = jbase0 + (t << 6);
        const int cur = t & 1;
        const short* vcur = &vs[cur][0];

        s16x8 vfA[4], vfB[4];
        LOADVF(vfA, 0, vcur);                     // HALF0 frags issued first

        s16x8 kA0n, kA1n;
        if (t + 1 < NT) {                         // prefetch next tile inputs
            VLOAD(jb + 64);
            kA0n = KLOAD(jb + 64);
            kA1n = KLOAD(jb + 96);
        }

        f32x16 s0 = __builtin_amdgcn_mfma_f32_32x32x16_bf16(kA0c, qB, zero16(), 0, 0, 0);
        LOADVF(vfB, 1, vcur);
        HALFP(s0, 0, vfA);
        LOADVF(vfA, 2, vcur);
        HALFP(s0, 1, vfB);
        f32x16 s1 = __builtin_amdgcn_mfma_f32_32x32x16_bf16(kA1c, qB, zero16(), 0, 0, 0);
        LOADVF(vfB, 3, vcur);
        HALFP(s1, 0, vfA);
        HALFP(s1, 1, vfB);

        if (t + 1 < NT) {                         // write-late into other buffer
            VSTORE(cur ^ 1);
            kA0c = kA0n; kA1c = kA1n;
        }
        __syncthreads();                          // single barrier per tile
    }

    float l_tot = l_acc + __shfl_xor(l_acc, 32);
    const int ncol = q0 + l31;

    if constexpr (DIRECT) {
        const float inv = 1.f / l_tot;
        #define EPID(Ov, ct) do {                                              \
            _Pragma("unroll")                                                  \
            for (int r = 0; r < 16; ++r) {                                     \
                const int c = (ct)*32 + (r&3) + 8*(r>>2) + (hi2<<2);           \
                const size_t off = (((size_t)(b * CDIM + c)) << 12) + ncol;    \
                out[off] = Ov[r] * inv + x[off];                               \
            } } while (0)
        EPID(O0, 0); EPID(O1, 1); EPID(O2, 2); EPID(O3, 3);
    } else {
        const int prow = (kc * 8 + b) * CDIM;
        #define EPIP(Ov, ct) do {                                              \
            _Pragma("unroll")                                                  \
            for (int r = 0; r < 16; ++r) {                                     \
                const int c = (ct)*32 + (r&3) + 8*(r>>2) + (hi2<<2);           \
                Op[(((size_t)(prow + c)) << 12) + ncol] = f2bf(Ov[r]);         \
            } } while (0)
        EPIP(O0, 0); EPIP(O1, 1); EPIP(O2, 2); EPIP(O3, 3);
        if (!hi2) lsum[(((size_t)(kc * 8 + b)) << 12) + ncol] = l_tot;
    }
}

// ---------------------------------------------------------------------------
// Kernel 3: combine split-K partials: out = (sum_k Op_k) / (sum_k l_k) + x
// ---------------------------------------------------------------------------
template<int KSPLIT>
__global__ __launch_bounds__(256) void attn_combine(
    const short* __restrict__ Op, const float* __restrict__ lsum,
    const float* __restrict__ x, float* __restrict__ out)
{
    __shared__ float linv[256];
    const int tid = threadIdx.x;
    const int bid = blockIdx.x;
    const int b   = bid >> 7;
    const int nb  = (bid >> 3) & 15;
    const int cb  = bid & 7;
    const int nbase = nb << 8;

    {
        float s = 0.f;
        #pragma unroll
        for (int k = 0; k < KSPLIT; ++k)
            s += lsum[(((size_t)(k * 8 + b)) << 12) + nbase + tid];
        linv[tid] = 1.f / s;
    }
    __syncthreads();

    const int n8 = (tid & 31) << 3;
    #pragma unroll
    for (int pass = 0; pass < 2; ++pass) {
        const int c = (cb << 4) + (pass << 3) + (tid >> 5);
        const size_t gbase = (((size_t)(b * CDIM + c)) << 12) + nbase + n8;
        float acc[8];
        #pragma unroll
        for (int j = 0; j < 8; ++j) acc[j] = 0.f;
        #pragma unroll
        for (int k = 0; k < KSPLIT; ++k) {
            s16x8 v = *(const s16x8*)(Op + (((size_t)((k * 8 + b) * CDIM + c)) << 12) + nbase + n8);
            #pragma unroll
            for (int j = 0; j < 8; ++j) acc[j] += bf2f(v[j]);
        }
        float4 li0 = *(const float4*)&linv[n8];
        float4 li1 = *(const float4*)&linv[n8 + 4];
        float4 x0  = *(const float4*)(x + gbase);
        float4 x1  = *(const float4*)(x + gbase + 4);
        float4 o0, o1;
        o0.x = acc[0] * li0.x + x0.x;  o0.y = acc[1] * li0.y + x0.y;
        o0.z = acc[2] * li0.z + x0.z;  o0.w = acc[3] * li0.w + x0.w;
        o1.x = acc[4] * li1.x + x1.x;  o1.y = acc[5] * li1.y + x1.y;
        o1.z = acc[6] * li1.z + x1.z;  o1.w = acc[7] * li1.w + x1.w;
        *(float4*)(out + gbase)     = o0;
        *(float4*)(out + gbase + 4) = o1;
    }
}

// ---------------------------------------------------------------------------
extern "C" void kernel_launch(void* const* d_in, const int* in_sizes, int n_in,
                              void* d_out, int out_size, void* d_ws, size_t ws_size,
                              hipStream_t stream) {
    const float* x  = (const float*)d_in[0];
    const float* wq = (const float*)d_in[1];
    const float* bq = (const float*)d_in[2];
    const float* wk = (const float*)d_in[3];
    const float* bk = (const float*)d_in[4];
    const float* wv = (const float*)d_in[5];
    const float* bv = (const float*)d_in[6];
    float* out = (float*)d_out;

    short* Qt = (short*)d_ws;                          // [8][4096][16] bf16, 1 MB
    short* Kt = Qt + (size_t)BATCH * NPIX * DK;        // [8][4096][16] bf16, 1 MB
    short* Vw = Kt + (size_t)BATCH * NPIX * DK;        // [8][128][4096] bf16, 8 MB
    short* Wpk = Vw + (size_t)BATCH * CDIM * NPIX;     // packed weights, 40 KB
    char*  extra = (char*)(Wpk + (size_t)WPFRAGS * 8);
    const size_t used    = (size_t)(extra - (char*)d_ws);
    const size_t opBytes = (size_t)BATCH * CDIM * NPIX * sizeof(short); // 8 MB
    const size_t lBytes  = (size_t)BATCH * NPIX * sizeof(float);        // 128 KB

    wprep<<<dim3(10), dim3(256), 0, stream>>>(wq, wk, wv, Wpk);
    qkv_proj<<<dim3(512), dim3(256), 0, stream>>>(x, Wpk, bq, bk, bv, Qt, Kt, Vw);

    if (used + 4 * (opBytes + lBytes) <= ws_size) {
        short* Opw = (short*)extra;
        float* ls  = (float*)(extra + 4 * opBytes);
        attn_part<4, false><<<dim3(8 * 32 * 4), dim3(256), 0, stream>>>(Qt, Kt, Vw, x, out, Opw, ls);
        attn_combine<4><<<dim3(1024), dim3(256), 0, stream>>>(Opw, ls, x, out);
    } else if (used + 2 * (opBytes + lBytes) <= ws_size) {
        short* Opw = (short*)extra;
        float* ls  = (float*)(extra + 2 * opBytes);
        attn_part<2, false><<<dim3(8 * 32 * 2), dim3(256), 0, stream>>>(Qt, Kt, Vw, x, out, Opw, ls);
        attn_combine<2><<<dim3(1024), dim3(256), 0, stream>>>(Opw, ls, x, out);
    } else {
        attn_part<1, true><<<dim3(8 * 32), dim3(256), 0, stream>>>(Qt, Kt, Vw, x, out, nullptr, nullptr);
    }
}

// Round 15
// 70.758 us; speedup vs baseline: 1.7027x; 1.1216x over previous
//
#include <hip/hip_runtime.h>
#include <hip/hip_bf16.h>

#define BATCH 8
#define CDIM  128
#define DK    16
#define NPIX  4096
#define VSTR  72   // conflict-free V LDS row stride (R8/R14-verified: 0 conflicts)

typedef __attribute__((ext_vector_type(4)))  float    f32x4;
typedef __attribute__((ext_vector_type(16))) float    f32x16;
typedef __attribute__((ext_vector_type(8)))  short    s16x8;
typedef __attribute__((ext_vector_type(4)))  unsigned u32x4;

__device__ __forceinline__ short f2bf(float f) {
    union { float fv; unsigned u; } un; un.fv = f;
    unsigned r = un.u + 0x7FFFu + ((un.u >> 16) & 1u);   // RTNE
    return (short)(r >> 16);
}
__device__ __forceinline__ float bf2f(short s) {
    union { unsigned u; float f; } un; un.u = ((unsigned)(unsigned short)s) << 16;
    return un.f;
}
__device__ __forceinline__ float fexp2(float x) {
#if __has_builtin(__builtin_amdgcn_exp2f)
    return __builtin_amdgcn_exp2f(x);
#else
    return exp2f(x);
#endif
}
__device__ __forceinline__ unsigned pkbf(float lo, float hi) {
    __hip_bfloat162 h = __float22bfloat162_rn(make_float2(lo, hi));
    return *reinterpret_cast<unsigned*>(&h);
}
__device__ __forceinline__ f32x16 zero16() {
    f32x16 z;
    #pragma unroll
    for (int i = 0; i < 16; ++i) z[i] = 0.f;
    return z;
}

#define C2F 0.36067376022224085f   // log2(e)/4
#define WPFRAGS (10 * 4 * 64)      // mt x kt x lane

// ---------------------------------------------------------------------------
// Kernel 0: pack weights fragment-ready bf16 (unchanged).
// ---------------------------------------------------------------------------
__global__ __launch_bounds__(256) void wprep(
    const float* __restrict__ wq, const float* __restrict__ wk,
    const float* __restrict__ wv, short* __restrict__ Wp)
{
    const int mt   = blockIdx.x;          // 0..9
    const int t    = threadIdx.x;
    const int kt   = t >> 6;
    const int lane = t & 63;
    const int m    = mt * 16 + (lane & 15);
    const int c0   = kt * 32 + ((lane >> 4) << 3);

    const float* src; float scl = 1.f;
    if (m < 16)      { src = wq + m * CDIM; scl = C2F; }
    else if (m < 32) { src = wk + (m - 16) * CDIM; }
    else             { src = wv + (m - 32) * CDIM; }

    s16x8 frag;
    #pragma unroll
    for (int i = 0; i < 8; ++i) frag[i] = f2bf(src[c0 + i] * scl);
    *(s16x8*)(Wp + (((size_t)(mt * 4 + kt) * 64 + lane) << 3)) = frag;
}

// ---------------------------------------------------------------------------
// Kernel 1: QKV projection via MFMA, no LDS (unchanged from R14).
// ---------------------------------------------------------------------------
__global__ __launch_bounds__(256) void qkv_proj(
    const float* __restrict__ x, const short* __restrict__ Wp,
    const float* __restrict__ bq, const float* __restrict__ bk,
    const float* __restrict__ bv,
    short* __restrict__ Qt, short* __restrict__ Kt, short* __restrict__ Vb)
{
    const int tid   = threadIdx.x;
    const int bid   = blockIdx.x;
    const int b     = bid >> 6;
    const int nbase = (bid & 63) << 6;

    const int lane = tid & 63;
    const int lo   = lane & 15;
    const int hi   = lane >> 4;
    const int n    = ((tid >> 6) << 4) + lo;    // pixel within block (0..63)
    const int ng   = nbase + n;

    const float* xb = x + (((size_t)(b * CDIM)) << 12) + ng;

    s16x8 bfr[4];
    #pragma unroll
    for (int kt = 0; kt < 4; ++kt) {
        const float* xp = xb + (((size_t)(kt * 32 + hi * 8)) << 12);
        float v0 = xp[0];
        float v1 = xp[(size_t)1 << 12];
        float v2 = xp[(size_t)2 << 12];
        float v3 = xp[(size_t)3 << 12];
        float v4 = xp[(size_t)4 << 12];
        float v5 = xp[(size_t)5 << 12];
        float v6 = xp[(size_t)6 << 12];
        float v7 = xp[(size_t)7 << 12];
        union { u32x4 u; s16x8 v; } pk;
        pk.u[0] = pkbf(v0, v1); pk.u[1] = pkbf(v2, v3);
        pk.u[2] = pkbf(v4, v5); pk.u[3] = pkbf(v6, v7);
        bfr[kt] = pk.v;
    }

    f32x4 acc[10];
    #pragma unroll
    for (int mt = 0; mt < 10; ++mt) { acc[mt][0]=0.f; acc[mt][1]=0.f; acc[mt][2]=0.f; acc[mt][3]=0.f; }

    #pragma unroll
    for (int kt = 0; kt < 4; ++kt) {
        #pragma unroll
        for (int mt = 0; mt < 10; ++mt) {
            const s16x8 af = *(const s16x8*)(Wp + (((size_t)(mt * 4 + kt) * 64 + lane) << 3));
            acc[mt] = __builtin_amdgcn_mfma_f32_16x16x32_bf16(af, bfr[kt], acc[mt], 0, 0, 0);
        }
    }

    const int m4 = hi << 2;
    {   // q rows (scaled): Qt[b][n][16]
        uint2 pk;
        pk.x = pkbf(acc[0][0] + bq[m4 + 0] * C2F, acc[0][1] + bq[m4 + 1] * C2F);
        pk.y = pkbf(acc[0][2] + bq[m4 + 2] * C2F, acc[0][3] + bq[m4 + 3] * C2F);
        *(uint2*)(Qt + ((((size_t)(b << 12)) + ng) << 4) + m4) = pk;
    }
    {   // k rows: Kt[b][n][16]
        uint2 pk;
        pk.x = pkbf(acc[1][0] + bk[m4 + 0], acc[1][1] + bk[m4 + 1]);
        pk.y = pkbf(acc[1][2] + bk[m4 + 2], acc[1][3] + bk[m4 + 3]);
        *(uint2*)(Kt + ((((size_t)(b << 12)) + ng) << 4) + m4) = pk;
    }
    #pragma unroll
    for (int mt = 2; mt < 10; ++mt) {     // v rows: Vb[b][c][n]
        #pragma unroll
        for (int r = 0; r < 4; ++r) {
            const int c = (mt - 2) * 16 + m4 + r;
            Vb[(((size_t)(b * CDIM + c)) << 12) + ng] = f2bf(acc[mt][r] + bv[c]);
        }
    }
}

// ---------------------------------------------------------------------------
// Kernel 2: flash attention partial — R14 structure + TWO independent
// query-block chains per wave (T15-style ILP): chains A (q0) and B (q0+128)
// share the staged K/V tile; B's exp/pack fills A's PV-MFMA latency shadow
// and vice versa.  s0 chains fully retired before s1 issues (register peak
// control); K regs reloaded AFTER their QK consumes them (free prefetch).
// __launch_bounds__(256,2): 256-reg/wave budget, est ~250 live.
// ---------------------------------------------------------------------------
template<int KSPLIT, bool DIRECT>
__global__ __launch_bounds__(256, 2) void attn_part(
    const short* __restrict__ Qt, const short* __restrict__ Kt,
    const short* __restrict__ Vb, const float* __restrict__ x,
    float* __restrict__ out, short* __restrict__ Op, float* __restrict__ lsum)
{
    constexpr int NKEY = NPIX / KSPLIT;
    constexpr int NT   = NKEY / 64;
    __shared__ __align__(16) short vs[2][CDIM * VSTR];   // 2 x 18 KB

    const int tid = threadIdx.x;
    const int bid = blockIdx.x;
    const int qb  = bid & 15;
    const int kc  = (bid >> 4) % KSPLIT;
    const int b   = bid / (16 * KSPLIT);
    const int q0A = qb * 256 + (tid >> 6) * 32;
    const int q0B = q0A + 128;
    const int l31 = tid & 31;
    const int hi2 = (tid >> 5) & 1;
    const int kq  = hi2 << 3;
    // K-row lane permutation: swap bit2<->bit3 (pi(s+4)=pi(s)+8)
    const int pi  = (l31 & ~12) | ((l31 & 4) << 1) | ((l31 & 8) >> 1);

    const s16x8 qBA = *(const s16x8*)(Qt + (((size_t)(b << 12) + q0A + l31) << 4) + kq);
    const s16x8 qBB = *(const s16x8*)(Qt + (((size_t)(b << 12) + q0B + l31) << 4) + kq);

    // V staging (conflict-free VSTR layout)
    const int j8  = tid & 7;
    const int cb8 = tid >> 3;
    const short* vsrc = Vb + (((size_t)(b * CDIM + cb8)) << 12) + (j8 << 3);
    const int vdoff = cb8 * VSTR + (j8 << 3);
    const size_t cstr = (size_t)32 << 12;

    const int jbase0 = kc * NKEY;
    const short* ktb = Kt + ((size_t)(b << 12) << 4);

    f32x16 OA0 = zero16(), OA1 = zero16(), OA2 = zero16(), OA3 = zero16();
    f32x16 OB0 = zero16(), OB1 = zero16(), OB2 = zero16(), OB3 = zero16();
    float l_accA = 0.f, l_accB = 0.f;

    s16x8 r0, r1, r2, r3;
    #define VLOAD(jb) do {                                   \
        r0 = *(const s16x8*)(vsrc + (jb));                   \
        r1 = *(const s16x8*)(vsrc + (jb) + cstr);            \
        r2 = *(const s16x8*)(vsrc + (jb) + 2 * cstr);        \
        r3 = *(const s16x8*)(vsrc + (jb) + 3 * cstr);        \
    } while (0)
    #define VSTORE(bufi) do {                                \
        short* vd_ = &vs[bufi][vdoff];                       \
        *(s16x8*)(vd_)             = r0;                     \
        *(s16x8*)(vd_ + 32 * VSTR) = r1;                     \
        *(s16x8*)(vd_ + 64 * VSTR) = r2;                     \
        *(s16x8*)(vd_ + 96 * VSTR) = r3;                     \
    } while (0)
    #define KLOAD(jb) (*(const s16x8*)(ktb + (((size_t)((jb) + pi)) << 4) + kq))
    #define LDSV(vb_, ct, ch) (*(const s16x8*)((vb_) + ((ct) * 32 + l31) * VSTR + ((ch) << 3)))
    #define LOADVF(dst, h, vb_) do {                         \
        const int ch_ = ((h) << 1) | hi2;                    \
        dst[0] = LDSV(vb_, 0, ch_);                          \
        dst[1] = LDSV(vb_, 1, ch_);                          \
        dst[2] = LDSV(vb_, 2, ch_);                          \
        dst[3] = LDSV(vb_, 3, ch_);                          \
    } while (0)

    #define HALFP(sv, ktl, vf, Oa, Ob, Oc, Od, lac) do {                        \
        float p0 = fexp2(sv[8*(ktl)+0]), p1 = fexp2(sv[8*(ktl)+1]);            \
        float p2 = fexp2(sv[8*(ktl)+2]), p3 = fexp2(sv[8*(ktl)+3]);            \
        float p4 = fexp2(sv[8*(ktl)+4]), p5 = fexp2(sv[8*(ktl)+5]);            \
        float p6 = fexp2(sv[8*(ktl)+6]), p7 = fexp2(sv[8*(ktl)+7]);            \
        lac += ((p0+p1)+(p2+p3)) + ((p4+p5)+(p6+p7));                          \
        union { u32x4 u; s16x8 v; } pc_;                                       \
        pc_.u[0] = pkbf(p0,p1); pc_.u[1] = pkbf(p2,p3);                        \
        pc_.u[2] = pkbf(p4,p5); pc_.u[3] = pkbf(p6,p7);                        \
        Oa = __builtin_amdgcn_mfma_f32_32x32x16_bf16(vf[0], pc_.v, Oa, 0,0,0); \
        Ob = __builtin_amdgcn_mfma_f32_32x32x16_bf16(vf[1], pc_.v, Ob, 0,0,0); \
        Oc = __builtin_amdgcn_mfma_f32_32x32x16_bf16(vf[2], pc_.v, Oc, 0,0,0); \
        Od = __builtin_amdgcn_mfma_f32_32x32x16_bf16(vf[3], pc_.v, Od, 0,0,0); \
    } while (0)
    #define HALF_A(sv, ktl, vf) HALFP(sv, ktl, vf, OA0, OA1, OA2, OA3, l_accA)
    #define HALF_B(sv, ktl, vf) HALFP(sv, ktl, vf, OB0, OB1, OB2, OB3, l_accB)

    // prologue
    VLOAD(jbase0);
    s16x8 kA0c = KLOAD(jbase0);
    s16x8 kA1c = KLOAD(jbase0 + 32);
    VSTORE(0);
    __syncthreads();

    for (int t = 0; t < NT; ++t) {
        const int jb  = jbase0 + (t << 6);
        const int cur = t & 1;
        const short* vcur = &vs[cur][0];

        s16x8 vfA[4], vfB[4];
        LOADVF(vfA, 0, vcur);

        f32x16 s0a = __builtin_amdgcn_mfma_f32_32x32x16_bf16(kA0c, qBA, zero16(), 0, 0, 0);
        f32x16 s0b = __builtin_amdgcn_mfma_f32_32x32x16_bf16(kA0c, qBB, zero16(), 0, 0, 0);

        if (t + 1 < NT) VLOAD(jb + 64);           // V issue-early (T14)

        LOADVF(vfB, 1, vcur);
        HALF_A(s0a, 0, vfA);
        HALF_B(s0b, 0, vfA);
        LOADVF(vfA, 2, vcur);
        HALF_A(s0a, 1, vfB);
        HALF_B(s0b, 1, vfB);                      // s0 chains retired here

        f32x16 s1a = __builtin_amdgcn_mfma_f32_32x32x16_bf16(kA1c, qBA, zero16(), 0, 0, 0);
        f32x16 s1b = __builtin_amdgcn_mfma_f32_32x32x16_bf16(kA1c, qBB, zero16(), 0, 0, 0);
        if (t + 1 < NT) {                         // free K prefetch: regs just consumed
            kA0c = KLOAD(jb + 64);
            kA1c = KLOAD(jb + 96);
        }
        LOADVF(vfB, 3, vcur);
        HALF_A(s1a, 0, vfA);
        HALF_B(s1b, 0, vfA);
        HALF_A(s1a, 1, vfB);
        HALF_B(s1b, 1, vfB);

        if (t + 1 < NT) VSTORE(cur ^ 1);          // write-late into other buffer
        __syncthreads();                          // single barrier per tile
    }

    float l_totA = l_accA + __shfl_xor(l_accA, 32);
    float l_totB = l_accB + __shfl_xor(l_accB, 32);
    const int ncolA = q0A + l31;
    const int ncolB = q0B + l31;

    if constexpr (DIRECT) {
        const float invA = 1.f / l_totA;
        const float invB = 1.f / l_totB;
        #define EPID(Ov, ct, ncol, inv) do {                                   \
            _Pragma("unroll")                                                  \
            for (int r = 0; r < 16; ++r) {                                     \
                const int c = (ct)*32 + (r&3) + 8*(r>>2) + (hi2<<2);           \
                const size_t off = (((size_t)(b * CDIM + c)) << 12) + (ncol);  \
                out[off] = Ov[r] * (inv) + x[off];                             \
            } } while (0)
        EPID(OA0, 0, ncolA, invA); EPID(OA1, 1, ncolA, invA);
        EPID(OA2, 2, ncolA, invA); EPID(OA3, 3, ncolA, invA);
        EPID(OB0, 0, ncolB, invB); EPID(OB1, 1, ncolB, invB);
        EPID(OB2, 2, ncolB, invB); EPID(OB3, 3, ncolB, invB);
    } else {
        const int prow = (kc * 8 + b) * CDIM;
        #define EPIP(Ov, ct, ncol) do {                                        \
            _Pragma("unroll")                                                  \
            for (int r = 0; r < 16; ++r) {                                     \
                const int c = (ct)*32 + (r&3) + 8*(r>>2) + (hi2<<2);           \
                Op[(((size_t)(prow + c)) << 12) + (ncol)] = f2bf(Ov[r]);       \
            } } while (0)
        EPIP(OA0, 0, ncolA); EPIP(OA1, 1, ncolA);
        EPIP(OA2, 2, ncolA); EPIP(OA3, 3, ncolA);
        EPIP(OB0, 0, ncolB); EPIP(OB1, 1, ncolB);
        EPIP(OB2, 2, ncolB); EPIP(OB3, 3, ncolB);
        if (!hi2) {
            lsum[(((size_t)(kc * 8 + b)) << 12) + ncolA] = l_totA;
            lsum[(((size_t)(kc * 8 + b)) << 12) + ncolB] = l_totB;
        }
    }
}

// ---------------------------------------------------------------------------
// Kernel 3: combine split-K partials: out = (sum_k Op_k) / (sum_k l_k) + x
// ---------------------------------------------------------------------------
template<int KSPLIT>
__global__ __launch_bounds__(256) void attn_combine(
    const short* __restrict__ Op, const float* __restrict__ lsum,
    const float* __restrict__ x, float* __restrict__ out)
{
    __shared__ float linv[256];
    const int tid = threadIdx.x;
    const int bid = blockIdx.x;
    const int b   = bid >> 7;
    const int nb  = (bid >> 3) & 15;
    const int cb  = bid & 7;
    const int nbase = nb << 8;

    {
        float s = 0.f;
        #pragma unroll
        for (int k = 0; k < KSPLIT; ++k)
            s += lsum[(((size_t)(k * 8 + b)) << 12) + nbase + tid];
        linv[tid] = 1.f / s;
    }
    __syncthreads();

    const int n8 = (tid & 31) << 3;
    #pragma unroll
    for (int pass = 0; pass < 2; ++pass) {
        const int c = (cb << 4) + (pass << 3) + (tid >> 5);
        const size_t gbase = (((size_t)(b * CDIM + c)) << 12) + nbase + n8;
        float acc[8];
        #pragma unroll
        for (int j = 0; j < 8; ++j) acc[j] = 0.f;
        #pragma unroll
        for (int k = 0; k < KSPLIT; ++k) {
            s16x8 v = *(const s16x8*)(Op + (((size_t)((k * 8 + b) * CDIM + c)) << 12) + nbase + n8);
            #pragma unroll
            for (int j = 0; j < 8; ++j) acc[j] += bf2f(v[j]);
        }
        float4 li0 = *(const float4*)&linv[n8];
        float4 li1 = *(const float4*)&linv[n8 + 4];
        float4 x0  = *(const float4*)(x + gbase);
        float4 x1  = *(const float4*)(x + gbase + 4);
        float4 o0, o1;
        o0.x = acc[0] * li0.x + x0.x;  o0.y = acc[1] * li0.y + x0.y;
        o0.z = acc[2] * li0.z + x0.z;  o0.w = acc[3] * li0.w + x0.w;
        o1.x = acc[4] * li1.x + x1.x;  o1.y = acc[5] * li1.y + x1.y;
        o1.z = acc[6] * li1.z + x1.z;  o1.w = acc[7] * li1.w + x1.w;
        *(float4*)(out + gbase)     = o0;
        *(float4*)(out + gbase + 4) = o1;
    }
}

// ---------------------------------------------------------------------------
extern "C" void kernel_launch(void* const* d_in, const int* in_sizes, int n_in,
                              void* d_out, int out_size, void* d_ws, size_t ws_size,
                              hipStream_t stream) {
    const float* x  = (const float*)d_in[0];
    const float* wq = (const float*)d_in[1];
    const float* bq = (const float*)d_in[2];
    const float* wk = (const float*)d_in[3];
    const float* bk = (const float*)d_in[4];
    const float* wv = (const float*)d_in[5];
    const float* bv = (const float*)d_in[6];
    float* out = (float*)d_out;

    short* Qt = (short*)d_ws;                          // [8][4096][16] bf16, 1 MB
    short* Kt = Qt + (size_t)BATCH * NPIX * DK;        // [8][4096][16] bf16, 1 MB
    short* Vw = Kt + (size_t)BATCH * NPIX * DK;        // [8][128][4096] bf16, 8 MB
    short* Wpk = Vw + (size_t)BATCH * CDIM * NPIX;     // packed weights, 40 KB
    char*  extra = (char*)(Wpk + (size_t)WPFRAGS * 8);
    const size_t used    = (size_t)(extra - (char*)d_ws);
    const size_t opBytes = (size_t)BATCH * CDIM * NPIX * sizeof(short); // 8 MB
    const size_t lBytes  = (size_t)BATCH * NPIX * sizeof(float);        // 128 KB

    wprep<<<dim3(10), dim3(256), 0, stream>>>(wq, wk, wv, Wpk);
    qkv_proj<<<dim3(512), dim3(256), 0, stream>>>(x, Wpk, bq, bk, bv, Qt, Kt, Vw);

    if (used + 4 * (opBytes + lBytes) <= ws_size) {
        short* Opw = (short*)extra;
        float* ls  = (float*)(extra + 4 * opBytes);
        attn_part<4, false><<<dim3(8 * 16 * 4), dim3(256), 0, stream>>>(Qt, Kt, Vw, x, out, Opw, ls);
        attn_combine<4><<<dim3(1024), dim3(256), 0, stream>>>(Opw, ls, x, out);
    } else if (used + 2 * (opBytes + lBytes) <= ws_size) {
        short* Opw = (short*)extra;
        float* ls  = (float*)(extra + 2 * opBytes);
        attn_part<2, false><<<dim3(8 * 16 * 2), dim3(256), 0, stream>>>(Qt, Kt, Vw, x, out, Opw, ls);
        attn_combine<2><<<dim3(1024), dim3(256), 0, stream>>>(Opw, ls, x, out);
    } else {
        attn_part<1, true><<<dim3(8 * 16), dim3(256), 0, stream>>>(Qt, Kt, Vw, x, out, nullptr, nullptr);
    }
}